// Round 13
// baseline (47.529 us; speedup 1.0000x reference)
//
#include <hip/hip_runtime.h>
#include <cstdint>

typedef unsigned long long u64;
typedef float f4 __attribute__((ext_vector_type(4)));

constexpr int S   = 160;          // D = H = W
constexpr int NB  = 4;            // batches
constexpr int PAD = 8;            // d/h padding in the global bit buffer (chain reach = 8)
constexpr int SP  = S + 2 * PAD;  // 176
constexpr int BUFW = NB * SP * 3 * SP;     // u64 per buffer (371,712)
constexpr int BLKC = 512;                  // chain kernel block size (8 waves)

__device__ __forceinline__ int widx(int b, int dp, int w, int hp) {
  return ((b * SP + dp) * 3 + w) * SP + hp;
}

// ---------------- full-row (3 u64 = 192 bits, k in [0,160)) helpers ----------------
struct R3 { u64 a, b, c; };

template <bool OR_> __device__ __forceinline__ u64 rop(u64 x, u64 y) { return OR_ ? (x | y) : (x & y); }
template <bool OR_> __device__ __forceinline__ R3 rop3(R3 x, R3 y) {
  return {rop<OR_>(x.a, y.a), rop<OR_>(x.b, y.b), rop<OR_>(x.c, y.c)};
}
template <int N> __device__ __forceinline__ R3 sl3(R3 x) {   // toward +k (zeros in)
  return {x.a << N, (x.b << N) | (x.a >> (64 - N)), (x.c << N) | (x.b >> (64 - N))};
}
template <int N> __device__ __forceinline__ R3 sr3(R3 x) {   // toward -k (zeros in)
  return {(x.a >> N) | (x.b << (64 - N)), (x.b >> N) | (x.c << (64 - N)), x.c >> N};
}
template <bool OR_> __device__ __forceinline__ R3 e1(R3 x) { // expand/shrink 1 along k
  return rop3<OR_>(rop3<OR_>(x, sl3<1>(x)), sr3<1>(x));
}
__device__ __forceinline__ R3 ldr(const u64* p) { return {p[0], p[1], p[2]}; }

// ---------------- fused 3-pass chain over an LDS tile ----------------
// Tile: 16x16 (d,h) output rows. IN 32x32 rows (halo 8), T1 32x20, T2 20x20.
// P1 (jk-plane): |dj|<=4 -> k±6 ; |dj|=5 -> ±5 ; |dj|=6 -> ±4
// P2 (ik-plane): |di|<=4 -> k±2 ; |di|=5 -> ±1 ; |di|=6 -> 0
// P3 (ij-diamond): (0,0),(±1,±1),(±2,0),(0,±2), no k reach
template <bool OR_, bool TOOUT>
__device__ void chain_body(const u64* __restrict__ src, u64* __restrict__ dstBits,
                           float* __restrict__ out, int b, int d0, int h0,
                           u64* sIN, u64* sT1, u64* sT2) {
  // load IN: rows d0-8..d0+23, h0-8..h0+23 (padded indices d0+di, h0+hi)
  for (int i = threadIdx.x; i < 32 * 32 * 3; i += BLKC) {
    const int hi = i % 32, w = (i / 32) % 3, di = i / 96;
    sIN[(di * 32 + hi) * 3 + w] = src[widx(b, d0 + di, w, h0 + hi)];
  }
  __syncthreads();

  // P1: outputs d:[-8..23] x h:[-2..17] -> T1[32][20]; input row = hh + 6 + dj
  for (int s = threadIdx.x; s < 32 * 20; s += BLKC) {
    const int dd = s / 20, hh = s % 20;
    const u64* base = sIN + (dd * 32 + hh) * 3;
    R3 G1 = ldr(base + 2 * 3);
#pragma unroll
    for (int r = 3; r <= 10; ++r) G1 = rop3<OR_>(G1, ldr(base + r * 3));
    R3 G2 = rop3<OR_>(ldr(base + 1 * 3), ldr(base + 11 * 3));
    R3 G3 = rop3<OR_>(ldr(base + 0 * 3), ldr(base + 12 * 3));
    R3 X = rop3<OR_>(rop3<OR_>(e1<OR_>(e1<OR_>(G1)), e1<OR_>(G2)), G3);
    R3 y = e1<OR_>(X);
    R3 R = rop3<OR_>(rop3<OR_>(y, sl3<3>(y)), sr3<3>(y));
    R.c &= 0xFFFFFFFFull;
    u64* q = sT1 + s * 3; q[0] = R.a; q[1] = R.b; q[2] = R.c;
  }
  __syncthreads();

  // P2: outputs d:[-2..17] x h:[-2..17] -> T2[20][20]; T1 row = dd + 6 + di
  for (int s = threadIdx.x; s < 20 * 20; s += BLKC) {
    const int dd = s / 20, hh = s % 20;
    const u64* base = sT1 + (dd * 20 + hh) * 3;   // row step = 60 u64
    R3 G1 = ldr(base + 2 * 60);
#pragma unroll
    for (int r = 3; r <= 10; ++r) G1 = rop3<OR_>(G1, ldr(base + r * 60));
    R3 G2 = rop3<OR_>(ldr(base + 1 * 60), ldr(base + 11 * 60));
    R3 G3 = rop3<OR_>(ldr(base + 0 * 60), ldr(base + 12 * 60));
    R3 X = rop3<OR_>(e1<OR_>(rop3<OR_>(e1<OR_>(G1), G2)), G3);
    X.c &= 0xFFFFFFFFull;
    u64* q = sT2 + s * 3; q[0] = X.a; q[1] = X.b; q[2] = X.c;
  }
  __syncthreads();

  // P3: final 16x16; T2 row = (dd+2+di, hh+2+dj)
  if (threadIdx.x < 256) {
    const int s = threadIdx.x;
    const int dd = s >> 4, hh = s & 15;
    const u64* t2 = sT2 + ((dd + 2) * 20 + (hh + 2)) * 3;
    R3 A = ldr(t2);
    A = rop3<OR_>(A, ldr(t2 + (20 + 1) * 3));  A = rop3<OR_>(A, ldr(t2 + (20 - 1) * 3));
    A = rop3<OR_>(A, ldr(t2 - (20 - 1) * 3));  A = rop3<OR_>(A, ldr(t2 - (20 + 1) * 3));
    A = rop3<OR_>(A, ldr(t2 + 40 * 3));        A = rop3<OR_>(A, ldr(t2 - 40 * 3));
    A = rop3<OR_>(A, ldr(t2 + 2 * 3));         A = rop3<OR_>(A, ldr(t2 - 2 * 3));
    A.c &= 0xFFFFFFFFull;
    if (TOOUT) {
      u64* q = sT1 + s * 3;                // T1 dead after P2 — reuse as OUT tile
      q[0] = A.a; q[1] = A.b; q[2] = A.c;
    } else {
      dstBits[widx(b, d0 + dd + PAD, 0, h0 + hh + PAD)] = A.a;
      dstBits[widx(b, d0 + dd + PAD, 1, h0 + hh + PAD)] = A.b;
      dstBits[widx(b, d0 + dd + PAD, 2, h0 + hh + PAD)] = A.c;
    }
  }
  if (TOOUT) {
    __syncthreads();
    // unpack OUT tile: 256 rows x 40 float4, coalesced, nontemporal
    for (int q = threadIdx.x; q < 16 * 16 * 40; q += BLKC) {
      const int r = q / 40, j = q % 40;
      const int dd = r >> 4, hh = r & 15;
      const u64 word = sT1[r * 3 + (j >> 4)];
      const unsigned nb = (unsigned)((word >> ((j & 15) * 4)) & 0xFull);
      f4 v;
      v.x = (float)(nb & 1u); v.y = (float)((nb >> 1) & 1u);
      v.z = (float)((nb >> 2) & 1u); v.w = (float)((nb >> 3) & 1u);
      const size_t e = ((size_t)((b * S + d0 + dd) * S + h0 + hh)) * S + j * 4;
      __builtin_nontemporal_store(v, reinterpret_cast<f4*>(out + e));
    }
  }
}

// PH0: first chain (even batch => OR/dilate). TOOUT: emit floats (second chain).
template <bool PH0, bool TOOUT>
__global__ __launch_bounds__(BLKC) void chain_k(const u64* __restrict__ src,
                                                u64* __restrict__ dstBits,
                                                float* __restrict__ out) {
  __shared__ u64 sIN[32 * 32 * 3];   // 24,576 B
  __shared__ u64 sT1[32 * 20 * 3];   // 15,360 B (reused as OUT tile in chain 2)
  __shared__ u64 sT2[20 * 20 * 3];   //  9,600 B
  const int blk = blockIdx.x;
  const int b = blk / 100, tile = blk % 100;
  const int d0 = (tile / 10) * 16, h0 = (tile % 10) * 16;
  const bool isor = (((b & 1) == 0) == PH0);
  if (isor) chain_body<true , TOOUT>(src, dstBits, out, b, d0, h0, sIN, sT1, sT2);
  else      chain_body<false, TOOUT>(src, dstBits, out, b, d0, h0, sIN, sT1, sT2);
}

// ---------------- pack: f4 aux -> nibbles in LDS -> u64 words (+ pad zeroing) ----------------
__device__ __forceinline__ u64 squash(u64 x) {  // 8 bytes of nibbles -> 32 bits
  x = (x | (x >> 4))  & 0x00FF00FF00FF00FFull;
  x = (x | (x >> 8))  & 0x0000FFFF0000FFFFull;
  x = (x | (x >> 16)) & 0x00000000FFFFFFFFull;
  return x;
}

__global__ __launch_bounds__(320) void pack_k(const float* __restrict__ aux,
                                              const float* __restrict__ inp,
                                              u64* __restrict__ dstA,
                                              u64* __restrict__ dstB) {
  // zero the pad halo of both buffers (disjoint from interior writes below)
  {
    const int g = blockIdx.x * 320 + threadIdx.x;
    if (g < BUFW) {
      const int hp = g % SP;
      const int dp = (g / (SP * 3)) % SP;
      if ((dp < PAD) | (dp >= S + PAD) | (hp < PAD) | (hp >= S + PAD)) {
        dstA[g] = 0ull; dstB[g] = 0ull;
      }
    }
  }
  __shared__ unsigned char nib[8][48];
  const int r   = threadIdx.x / 40;   // 8 rows per block
  const int pos = threadIdx.x % 40;   // 4 elements each
  const int row = blockIdx.x * 8 + r;
  const size_t ebase = (size_t)row * S + pos * 4;

  const f4 a = __builtin_nontemporal_load(reinterpret_cast<const f4*>(aux) + (row * 40 + pos));
  unsigned n = 0;
  if (a.x < 0.0f) n |= 1u; else if (a.x == 0.0f) { if (inp[ebase + 0] != 0.0f) n |= 1u; }
  if (a.y < 0.0f) n |= 2u; else if (a.y == 0.0f) { if (inp[ebase + 1] != 0.0f) n |= 2u; }
  if (a.z < 0.0f) n |= 4u; else if (a.z == 0.0f) { if (inp[ebase + 2] != 0.0f) n |= 4u; }
  if (a.w < 0.0f) n |= 8u; else if (a.w == 0.0f) { if (inp[ebase + 3] != 0.0f) n |= 8u; }
  nib[r][pos] = (unsigned char)n;
  if (threadIdx.x < 64) nib[threadIdx.x >> 3][40 + (threadIdx.x & 7)] = 0;
  __syncthreads();

  if (threadIdx.x < 24) {
    const int rr = threadIdx.x & 7;
    const int w  = threadIdx.x >> 3;
    const u64 x0 = *reinterpret_cast<const u64*>(&nib[rr][w * 16]);
    const u64 x1 = *reinterpret_cast<const u64*>(&nib[rr][w * 16 + 8]);
    const u64 word = squash(x0) | (squash(x1) << 32);
    const int grow = blockIdx.x * 8 + rr;
    const int h = grow % S, d = (grow / S) % S, b = grow / (S * S);
    dstA[widx(b, d + PAD, w, h + PAD)] = word;
  }
}

extern "C" void kernel_launch(void* const* d_in, const int* in_sizes, int n_in,
                              void* d_out, int out_size, void* d_ws, size_t ws_size,
                              hipStream_t stream) {
  (void)in_sizes; (void)n_in; (void)out_size; (void)ws_size;
  const float* inp = (const float*)d_in[0];
  const float* aux = (const float*)d_in[1];
  float* out = (float*)d_out;

  u64* bufA = (u64*)d_ws;
  u64* bufB = bufA + BUFW;

  const int ROWS = NB * S * S;            // 102400
  pack_k<<<ROWS / 8, 320, 0, stream>>>(aux, inp, bufA, bufB);   // 12800 blocks

  const int CG = NB * 100;                // 400 tile blocks
  chain_k<true , false><<<CG, BLKC, 0, stream>>>(bufA, bufB, out);  // chain 1 -> bits
  chain_k<false, true ><<<CG, BLKC, 0, stream>>>(bufB, bufA, out);  // chain 2 -> floats
}

// Round 14
// 41.178 us; speedup vs baseline: 1.1542x; 1.1542x over previous
//
#include <hip/hip_runtime.h>
#include <cstdint>

typedef unsigned long long u64;

constexpr int S   = 160;          // D = H = W
constexpr int NB  = 4;            // batches
constexpr int PAD = 8;            // d/h padding in the global bit buffer (chain reach = 8)
constexpr int SP  = S + 2 * PAD;  // 176
constexpr int BUFW = NB * SP * 3 * SP;     // u64 per buffer (371,712)
constexpr int BLKC = 512;                  // chain kernel block size (8 waves)

__device__ __forceinline__ int widx(int b, int dp, int w, int hp) {
  return ((b * SP + dp) * 3 + w) * SP + hp;
}

// ---------------- full-row (3 u64 = 192 bits, k in [0,160)) helpers ----------------
struct R3 { u64 a, b, c; };

template <bool OR_> __device__ __forceinline__ u64 rop(u64 x, u64 y) { return OR_ ? (x | y) : (x & y); }
template <bool OR_> __device__ __forceinline__ R3 rop3(R3 x, R3 y) {
  return {rop<OR_>(x.a, y.a), rop<OR_>(x.b, y.b), rop<OR_>(x.c, y.c)};
}
template <int N> __device__ __forceinline__ R3 sl3(R3 x) {   // toward +k (zeros in)
  return {x.a << N, (x.b << N) | (x.a >> (64 - N)), (x.c << N) | (x.b >> (64 - N))};
}
template <int N> __device__ __forceinline__ R3 sr3(R3 x) {   // toward -k (zeros in)
  return {(x.a >> N) | (x.b << (64 - N)), (x.b >> N) | (x.c << (64 - N)), x.c >> N};
}
template <bool OR_> __device__ __forceinline__ R3 e1(R3 x) { // expand/shrink 1 along k
  return rop3<OR_>(rop3<OR_>(x, sl3<1>(x)), sr3<1>(x));
}
__device__ __forceinline__ R3 ldr(const u64* p) { return {p[0], p[1], p[2]}; }

// ---------------- fused 3-pass chain over an LDS tile ----------------
// Tile: 16x16 (d,h) output rows. IN 32x32 rows (halo 8), T1 32x20, T2 20x20.
// P1 (jk-plane): |dj|<=4 -> k±6 ; |dj|=5 -> ±5 ; |dj|=6 -> ±4
// P2 (ik-plane): |di|<=4 -> k±2 ; |di|=5 -> ±1 ; |di|=6 -> 0
// P3 (ij-diamond): (0,0),(±1,±1),(±2,0),(0,±2), no k reach
template <bool OR_, bool TOOUT>
__device__ void chain_body(const u64* __restrict__ src, u64* __restrict__ dstBits,
                           float* __restrict__ out, int b, int d0, int h0,
                           u64* sIN, u64* sT1, u64* sT2) {
  // load IN: rows d0-8..d0+23, h0-8..h0+23 (padded indices d0+di, h0+hi)
  for (int i = threadIdx.x; i < 32 * 32 * 3; i += BLKC) {
    const int hi = i % 32, w = (i / 32) % 3, di = i / 96;
    sIN[(di * 32 + hi) * 3 + w] = src[widx(b, d0 + di, w, h0 + hi)];
  }
  __syncthreads();

  // P1: outputs d:[-8..23] x h:[-2..17] -> T1[32][20]; input row = hh + 6 + dj
  for (int s = threadIdx.x; s < 32 * 20; s += BLKC) {
    const int dd = s / 20, hh = s % 20;
    const u64* base = sIN + (dd * 32 + hh) * 3;
    R3 G1 = ldr(base + 2 * 3);
#pragma unroll
    for (int r = 3; r <= 10; ++r) G1 = rop3<OR_>(G1, ldr(base + r * 3));
    R3 G2 = rop3<OR_>(ldr(base + 1 * 3), ldr(base + 11 * 3));
    R3 G3 = rop3<OR_>(ldr(base + 0 * 3), ldr(base + 12 * 3));
    R3 X = rop3<OR_>(rop3<OR_>(e1<OR_>(e1<OR_>(G1)), e1<OR_>(G2)), G3);
    R3 y = e1<OR_>(X);
    R3 R = rop3<OR_>(rop3<OR_>(y, sl3<3>(y)), sr3<3>(y));
    R.c &= 0xFFFFFFFFull;
    u64* q = sT1 + s * 3; q[0] = R.a; q[1] = R.b; q[2] = R.c;
  }
  __syncthreads();

  // P2: outputs d:[-2..17] x h:[-2..17] -> T2[20][20]; T1 row = dd + 6 + di
  for (int s = threadIdx.x; s < 20 * 20; s += BLKC) {
    const int dd = s / 20, hh = s % 20;
    const u64* base = sT1 + (dd * 20 + hh) * 3;   // row step = 60 u64
    R3 G1 = ldr(base + 2 * 60);
#pragma unroll
    for (int r = 3; r <= 10; ++r) G1 = rop3<OR_>(G1, ldr(base + r * 60));
    R3 G2 = rop3<OR_>(ldr(base + 1 * 60), ldr(base + 11 * 60));
    R3 G3 = rop3<OR_>(ldr(base + 0 * 60), ldr(base + 12 * 60));
    R3 X = rop3<OR_>(e1<OR_>(rop3<OR_>(e1<OR_>(G1), G2)), G3);
    X.c &= 0xFFFFFFFFull;
    u64* q = sT2 + s * 3; q[0] = X.a; q[1] = X.b; q[2] = X.c;
  }
  __syncthreads();

  // P3: final 16x16; T2 row = (dd+2+di, hh+2+dj)
  if (threadIdx.x < 256) {
    const int s = threadIdx.x;
    const int dd = s >> 4, hh = s & 15;
    const u64* t2 = sT2 + ((dd + 2) * 20 + (hh + 2)) * 3;
    R3 A = ldr(t2);
    A = rop3<OR_>(A, ldr(t2 + (20 + 1) * 3));  A = rop3<OR_>(A, ldr(t2 + (20 - 1) * 3));
    A = rop3<OR_>(A, ldr(t2 - (20 - 1) * 3));  A = rop3<OR_>(A, ldr(t2 - (20 + 1) * 3));
    A = rop3<OR_>(A, ldr(t2 + 40 * 3));        A = rop3<OR_>(A, ldr(t2 - 40 * 3));
    A = rop3<OR_>(A, ldr(t2 + 2 * 3));         A = rop3<OR_>(A, ldr(t2 - 2 * 3));
    A.c &= 0xFFFFFFFFull;
    if (TOOUT) {
      u64* q = sT1 + s * 3;                // T1 dead after P2 — reuse as OUT tile
      q[0] = A.a; q[1] = A.b; q[2] = A.c;
    } else {
      dstBits[widx(b, d0 + dd + PAD, 0, h0 + hh + PAD)] = A.a;
      dstBits[widx(b, d0 + dd + PAD, 1, h0 + hh + PAD)] = A.b;
      dstBits[widx(b, d0 + dd + PAD, 2, h0 + hh + PAD)] = A.c;
    }
  }
  if (TOOUT) {
    __syncthreads();
    // unpack OUT tile: 256 rows x 40 float4, coalesced
    for (int q = threadIdx.x; q < 16 * 16 * 40; q += BLKC) {
      const int r = q / 40, j = q % 40;
      const int dd = r >> 4, hh = r & 15;
      const u64 word = sT1[r * 3 + (j >> 4)];
      const unsigned nb = (unsigned)((word >> ((j & 15) * 4)) & 0xFull);
      float4 v;
      v.x = (float)(nb & 1u); v.y = (float)((nb >> 1) & 1u);
      v.z = (float)((nb >> 2) & 1u); v.w = (float)((nb >> 3) & 1u);
      const size_t e = ((size_t)((b * S + d0 + dd) * S + h0 + hh)) * S + j * 4;
      *reinterpret_cast<float4*>(out + e) = v;
    }
  }
}

// PH0: first chain (even batch => OR/dilate). TOOUT: emit floats (second chain).
template <bool PH0, bool TOOUT>
__global__ __launch_bounds__(BLKC) void chain_k(const u64* __restrict__ src,
                                                u64* __restrict__ dstBits,
                                                float* __restrict__ out) {
  __shared__ u64 sIN[32 * 32 * 3];   // 24,576 B
  __shared__ u64 sT1[32 * 20 * 3];   // 15,360 B (reused as OUT tile in chain 2)
  __shared__ u64 sT2[20 * 20 * 3];   //  9,600 B
  const int blk = blockIdx.x;
  const int b = blk / 100, tile = blk % 100;
  const int d0 = (tile / 10) * 16, h0 = (tile % 10) * 16;
  const bool isor = (((b & 1) == 0) == PH0);
  if (isor) chain_body<true , TOOUT>(src, dstBits, out, b, d0, h0, sIN, sT1, sT2);
  else      chain_body<false, TOOUT>(src, dstBits, out, b, d0, h0, sIN, sT1, sT2);
}

// ---------------- pack: float4 aux -> nibbles in LDS -> u64 words (+ pad zeroing) ----------------
__device__ __forceinline__ u64 squash(u64 x) {  // 8 bytes of nibbles -> 32 bits
  x = (x | (x >> 4))  & 0x00FF00FF00FF00FFull;
  x = (x | (x >> 8))  & 0x0000FFFF0000FFFFull;
  x = (x | (x >> 16)) & 0x00000000FFFFFFFFull;
  return x;
}

__global__ __launch_bounds__(320) void pack_k(const float* __restrict__ aux,
                                              const float* __restrict__ inp,
                                              u64* __restrict__ dstA,
                                              u64* __restrict__ dstB) {
  // zero the pad halo of both buffers (disjoint from interior writes below)
  {
    const int g = blockIdx.x * 320 + threadIdx.x;
    if (g < BUFW) {
      const int hp = g % SP;
      const int dp = (g / (SP * 3)) % SP;
      if ((dp < PAD) | (dp >= S + PAD) | (hp < PAD) | (hp >= S + PAD)) {
        dstA[g] = 0ull; dstB[g] = 0ull;
      }
    }
  }
  __shared__ unsigned char nib[8][48];
  const int r   = threadIdx.x / 40;   // 8 rows per block
  const int pos = threadIdx.x % 40;   // 4 elements each
  const int row = blockIdx.x * 8 + r;
  const size_t ebase = (size_t)row * S + pos * 4;

  const float4 a = reinterpret_cast<const float4*>(aux)[row * 40 + pos];
  unsigned n = 0;
  if (a.x < 0.0f) n |= 1u; else if (a.x == 0.0f) { if (inp[ebase + 0] != 0.0f) n |= 1u; }
  if (a.y < 0.0f) n |= 2u; else if (a.y == 0.0f) { if (inp[ebase + 1] != 0.0f) n |= 2u; }
  if (a.z < 0.0f) n |= 4u; else if (a.z == 0.0f) { if (inp[ebase + 2] != 0.0f) n |= 4u; }
  if (a.w < 0.0f) n |= 8u; else if (a.w == 0.0f) { if (inp[ebase + 3] != 0.0f) n |= 8u; }
  nib[r][pos] = (unsigned char)n;
  if (threadIdx.x < 64) nib[threadIdx.x >> 3][40 + (threadIdx.x & 7)] = 0;
  __syncthreads();

  if (threadIdx.x < 24) {
    const int rr = threadIdx.x & 7;
    const int w  = threadIdx.x >> 3;
    const u64 x0 = *reinterpret_cast<const u64*>(&nib[rr][w * 16]);
    const u64 x1 = *reinterpret_cast<const u64*>(&nib[rr][w * 16 + 8]);
    const u64 word = squash(x0) | (squash(x1) << 32);
    const int grow = blockIdx.x * 8 + rr;
    const int h = grow % S, d = (grow / S) % S, b = grow / (S * S);
    dstA[widx(b, d + PAD, w, h + PAD)] = word;
  }
}

extern "C" void kernel_launch(void* const* d_in, const int* in_sizes, int n_in,
                              void* d_out, int out_size, void* d_ws, size_t ws_size,
                              hipStream_t stream) {
  (void)in_sizes; (void)n_in; (void)out_size; (void)ws_size;
  const float* inp = (const float*)d_in[0];
  const float* aux = (const float*)d_in[1];
  float* out = (float*)d_out;

  u64* bufA = (u64*)d_ws;
  u64* bufB = bufA + BUFW;

  const int ROWS = NB * S * S;            // 102400
  pack_k<<<ROWS / 8, 320, 0, stream>>>(aux, inp, bufA, bufB);   // 12800 blocks

  const int CG = NB * 100;                // 400 tile blocks
  chain_k<true , false><<<CG, BLKC, 0, stream>>>(bufA, bufB, out);  // chain 1 -> bits
  chain_k<false, true ><<<CG, BLKC, 0, stream>>>(bufB, bufA, out);  // chain 2 -> floats
}

// Round 15
// 40.944 us; speedup vs baseline: 1.1608x; 1.0057x over previous
//
#include <hip/hip_runtime.h>
#include <cstdint>

typedef unsigned long long u64;

constexpr int S   = 160;          // D = H = W
constexpr int NB  = 4;            // batches
constexpr int PAD = 8;            // d/h padding in the global bit buffer (chain reach = 8)
constexpr int SP  = S + 2 * PAD;  // 176
constexpr int BUFW = NB * SP * 3 * SP;     // u64 per buffer (371,712)
constexpr int BLKC = 512;                  // chain kernel block size (8 waves)

// chain tile: TD x TH output rows -> 8 x 16 tiles -> 512 blocks = exactly 2/CU on 256 CUs
constexpr int TD = 20, TH = 10;
constexpr int IND = TD + 16;               // 36 d-rows (halo 8)
constexpr int INH = TH + 16;               // 26 h-cols (halo 8)
constexpr int T1H = TH + 4;                // 14 (h: -2..TH+1)
constexpr int T2D = TD + 4;                // 24 (d: -2..TD+1)
constexpr int NTD = S / TD, NTH = S / TH;  // 8 x 16
constexpr int GRIDC = NB * NTD * NTH;      // 512 blocks

__device__ __forceinline__ int widx(int b, int dp, int w, int hp) {
  return ((b * SP + dp) * 3 + w) * SP + hp;
}

// ---------------- full-row (3 u64 = 192 bits, k in [0,160)) helpers ----------------
struct R3 { u64 a, b, c; };

template <bool OR_> __device__ __forceinline__ u64 rop(u64 x, u64 y) { return OR_ ? (x | y) : (x & y); }
template <bool OR_> __device__ __forceinline__ R3 rop3(R3 x, R3 y) {
  return {rop<OR_>(x.a, y.a), rop<OR_>(x.b, y.b), rop<OR_>(x.c, y.c)};
}
template <int N> __device__ __forceinline__ R3 sl3(R3 x) {   // toward +k (zeros in)
  return {x.a << N, (x.b << N) | (x.a >> (64 - N)), (x.c << N) | (x.b >> (64 - N))};
}
template <int N> __device__ __forceinline__ R3 sr3(R3 x) {   // toward -k (zeros in)
  return {(x.a >> N) | (x.b << (64 - N)), (x.b >> N) | (x.c << (64 - N)), x.c >> N};
}
template <bool OR_> __device__ __forceinline__ R3 e1(R3 x) { // expand/shrink 1 along k
  return rop3<OR_>(rop3<OR_>(x, sl3<1>(x)), sr3<1>(x));
}
__device__ __forceinline__ R3 ldr(const u64* p) { return {p[0], p[1], p[2]}; }

// ---------------- fused 3-pass chain over an LDS tile ----------------
// P1 (jk-plane): |dj|<=4 -> k±6 ; |dj|=5 -> ±5 ; |dj|=6 -> ±4
// P2 (ik-plane): |di|<=4 -> k±2 ; |di|=5 -> ±1 ; |di|=6 -> 0
// P3 (ij-diamond): (0,0),(±1,±1),(±2,0),(0,±2), no k reach
template <bool OR_, bool TOOUT>
__device__ void chain_body(const u64* __restrict__ src, u64* __restrict__ dstBits,
                           float* __restrict__ out, int b, int d0, int h0,
                           u64* sIN, u64* sT1, u64* sT2) {
  // load IN: d rows d0-8..d0+TD+7, h cols h0-8..h0+TH+7 (padded coords d0+di, h0+hi)
  for (int i = threadIdx.x; i < IND * INH * 3; i += BLKC) {
    const int hi = i % INH, w = (i / INH) % 3, di = i / (3 * INH);
    sIN[(di * INH + hi) * 3 + w] = src[widx(b, d0 + di, w, h0 + hi)];
  }
  __syncthreads();

  // P1: out d:[-8..TD+7] x h:[-2..TH+1] -> T1[IND][T1H]; IN col = hh + r, r in [0..12]
  for (int s = threadIdx.x; s < IND * T1H; s += BLKC) {
    const int dd = s / T1H, hh = s % T1H;
    const u64* base = sIN + (dd * INH + hh) * 3;
    R3 G1 = ldr(base + 2 * 3);
#pragma unroll
    for (int r = 3; r <= 10; ++r) G1 = rop3<OR_>(G1, ldr(base + r * 3));
    R3 G2 = rop3<OR_>(ldr(base + 1 * 3), ldr(base + 11 * 3));
    R3 G3 = rop3<OR_>(ldr(base + 0 * 3), ldr(base + 12 * 3));
    R3 X = rop3<OR_>(rop3<OR_>(e1<OR_>(e1<OR_>(G1)), e1<OR_>(G2)), G3);
    R3 y = e1<OR_>(X);
    R3 R = rop3<OR_>(rop3<OR_>(y, sl3<3>(y)), sr3<3>(y));
    R.c &= 0xFFFFFFFFull;
    u64* q = sT1 + s * 3; q[0] = R.a; q[1] = R.b; q[2] = R.c;
  }
  __syncthreads();

  // P2: out d:[-2..TD+1] x h:[-2..TH+1] -> T2[T2D][T1H]; T1 row = dd + r
  for (int s = threadIdx.x; s < T2D * T1H; s += BLKC) {
    const int dd = s / T1H, hh = s % T1H;
    const u64* base = sT1 + (dd * T1H + hh) * 3;   // d-row step = T1H*3 u64
    R3 G1 = ldr(base + 2 * (T1H * 3));
#pragma unroll
    for (int r = 3; r <= 10; ++r) G1 = rop3<OR_>(G1, ldr(base + r * (T1H * 3)));
    R3 G2 = rop3<OR_>(ldr(base + 1 * (T1H * 3)), ldr(base + 11 * (T1H * 3)));
    R3 G3 = rop3<OR_>(ldr(base + 0 * (T1H * 3)), ldr(base + 12 * (T1H * 3)));
    R3 X = rop3<OR_>(e1<OR_>(rop3<OR_>(e1<OR_>(G1), G2)), G3);
    X.c &= 0xFFFFFFFFull;
    u64* q = sT2 + s * 3; q[0] = X.a; q[1] = X.b; q[2] = X.c;
  }
  __syncthreads();

  // P3: final TD x TH; T2 center (dd+2, hh+2), row stride T1H
  if (threadIdx.x < TD * TH) {
    const int s = threadIdx.x;
    const int dd = s / TH, hh = s % TH;
    const u64* t2 = sT2 + ((dd + 2) * T1H + (hh + 2)) * 3;
    R3 A = ldr(t2);
    A = rop3<OR_>(A, ldr(t2 + (T1H + 1) * 3));  A = rop3<OR_>(A, ldr(t2 + (T1H - 1) * 3));
    A = rop3<OR_>(A, ldr(t2 - (T1H - 1) * 3));  A = rop3<OR_>(A, ldr(t2 - (T1H + 1) * 3));
    A = rop3<OR_>(A, ldr(t2 + 2 * T1H * 3));    A = rop3<OR_>(A, ldr(t2 - 2 * T1H * 3));
    A = rop3<OR_>(A, ldr(t2 + 2 * 3));          A = rop3<OR_>(A, ldr(t2 - 2 * 3));
    A.c &= 0xFFFFFFFFull;
    if (TOOUT) {
      u64* q = sT1 + s * 3;                // T1 dead after P2 — reuse as OUT tile
      q[0] = A.a; q[1] = A.b; q[2] = A.c;
    } else {
      dstBits[widx(b, d0 + dd + PAD, 0, h0 + hh + PAD)] = A.a;
      dstBits[widx(b, d0 + dd + PAD, 1, h0 + hh + PAD)] = A.b;
      dstBits[widx(b, d0 + dd + PAD, 2, h0 + hh + PAD)] = A.c;
    }
  }
  if (TOOUT) {
    __syncthreads();
    // unpack OUT tile: TD*TH rows x 40 float4, coalesced
    for (int q = threadIdx.x; q < TD * TH * 40; q += BLKC) {
      const int r = q / 40, j = q % 40;
      const int dd = r / TH, hh = r % TH;
      const u64 word = sT1[r * 3 + (j >> 4)];
      const unsigned nb = (unsigned)((word >> ((j & 15) * 4)) & 0xFull);
      float4 v;
      v.x = (float)(nb & 1u); v.y = (float)((nb >> 1) & 1u);
      v.z = (float)((nb >> 2) & 1u); v.w = (float)((nb >> 3) & 1u);
      const size_t e = ((size_t)((b * S + d0 + dd) * S + h0 + hh)) * S + j * 4;
      *reinterpret_cast<float4*>(out + e) = v;
    }
  }
}

// PH0: first chain (even batch => OR/dilate). TOOUT: emit floats (second chain).
template <bool PH0, bool TOOUT>
__global__ __launch_bounds__(BLKC) void chain_k(const u64* __restrict__ src,
                                                u64* __restrict__ dstBits,
                                                float* __restrict__ out) {
  __shared__ u64 sIN[IND * INH * 3];   // 2808 u64 = 22,464 B
  __shared__ u64 sT1[IND * T1H * 3];   // 1512 u64 = 12,096 B (reused as OUT tile)
  __shared__ u64 sT2[T2D * T1H * 3];   // 1008 u64 =  8,064 B   => 42.6 KB total
  const int blk = blockIdx.x;
  const int b = blk / (NTD * NTH), tile = blk % (NTD * NTH);
  const int d0 = (tile / NTH) * TD, h0 = (tile % NTH) * TH;
  const bool isor = (((b & 1) == 0) == PH0);
  if (isor) chain_body<true , TOOUT>(src, dstBits, out, b, d0, h0, sIN, sT1, sT2);
  else      chain_body<false, TOOUT>(src, dstBits, out, b, d0, h0, sIN, sT1, sT2);
}

// ---------------- pack: float4 aux -> nibbles in LDS -> u64 words (+ pad zeroing) ----------------
__device__ __forceinline__ u64 squash(u64 x) {  // 8 bytes of nibbles -> 32 bits
  x = (x | (x >> 4))  & 0x00FF00FF00FF00FFull;
  x = (x | (x >> 8))  & 0x0000FFFF0000FFFFull;
  x = (x | (x >> 16)) & 0x00000000FFFFFFFFull;
  return x;
}

__global__ __launch_bounds__(320) void pack_k(const float* __restrict__ aux,
                                              const float* __restrict__ inp,
                                              u64* __restrict__ dstA,
                                              u64* __restrict__ dstB) {
  // zero the pad halo of both buffers (disjoint from interior writes below)
  {
    const int g = blockIdx.x * 320 + threadIdx.x;
    if (g < BUFW) {
      const int hp = g % SP;
      const int dp = (g / (SP * 3)) % SP;
      if ((dp < PAD) | (dp >= S + PAD) | (hp < PAD) | (hp >= S + PAD)) {
        dstA[g] = 0ull; dstB[g] = 0ull;
      }
    }
  }
  __shared__ unsigned char nib[8][48];
  const int r   = threadIdx.x / 40;   // 8 rows per block
  const int pos = threadIdx.x % 40;   // 4 elements each
  const int row = blockIdx.x * 8 + r;
  const size_t ebase = (size_t)row * S + pos * 4;

  const float4 a = reinterpret_cast<const float4*>(aux)[row * 40 + pos];
  unsigned n = 0;
  if (a.x < 0.0f) n |= 1u; else if (a.x == 0.0f) { if (inp[ebase + 0] != 0.0f) n |= 1u; }
  if (a.y < 0.0f) n |= 2u; else if (a.y == 0.0f) { if (inp[ebase + 1] != 0.0f) n |= 2u; }
  if (a.z < 0.0f) n |= 4u; else if (a.z == 0.0f) { if (inp[ebase + 2] != 0.0f) n |= 4u; }
  if (a.w < 0.0f) n |= 8u; else if (a.w == 0.0f) { if (inp[ebase + 3] != 0.0f) n |= 8u; }
  nib[r][pos] = (unsigned char)n;
  if (threadIdx.x < 64) nib[threadIdx.x >> 3][40 + (threadIdx.x & 7)] = 0;
  __syncthreads();

  if (threadIdx.x < 24) {
    const int rr = threadIdx.x & 7;
    const int w  = threadIdx.x >> 3;
    const u64 x0 = *reinterpret_cast<const u64*>(&nib[rr][w * 16]);
    const u64 x1 = *reinterpret_cast<const u64*>(&nib[rr][w * 16 + 8]);
    const u64 word = squash(x0) | (squash(x1) << 32);
    const int grow = blockIdx.x * 8 + rr;
    const int h = grow % S, d = (grow / S) % S, b = grow / (S * S);
    dstA[widx(b, d + PAD, w, h + PAD)] = word;
  }
}

extern "C" void kernel_launch(void* const* d_in, const int* in_sizes, int n_in,
                              void* d_out, int out_size, void* d_ws, size_t ws_size,
                              hipStream_t stream) {
  (void)in_sizes; (void)n_in; (void)out_size; (void)ws_size;
  const float* inp = (const float*)d_in[0];
  const float* aux = (const float*)d_in[1];
  float* out = (float*)d_out;

  u64* bufA = (u64*)d_ws;
  u64* bufB = bufA + BUFW;

  const int ROWS = NB * S * S;            // 102400
  pack_k<<<ROWS / 8, 320, 0, stream>>>(aux, inp, bufA, bufB);   // 12800 blocks

  chain_k<true , false><<<GRIDC, BLKC, 0, stream>>>(bufA, bufB, out);  // chain 1 -> bits
  chain_k<false, true ><<<GRIDC, BLKC, 0, stream>>>(bufB, bufA, out);  // chain 2 -> floats
}